// Round 5
// baseline (1476.946 us; speedup 1.0000x reference)
//
#include <hip/hip_runtime.h>
#include <stdint.h>
#include <stddef.h>

#define N_NODES 20000
#define N_EDGES 320000

typedef unsigned short u16;

__device__ __forceinline__ float bf2f(u16 u) {
    union { unsigned int i; float f; } v; v.i = ((unsigned int)u) << 16; return v.f;
}
__device__ __forceinline__ u16 f2bf(float f) {
    union { float f; unsigned int i; } v; v.f = f;
    unsigned int x = v.i;
    unsigned int r = x + 0x7fffu + ((x >> 16) & 1u);
    return (u16)(r >> 16);
}
__device__ __forceinline__ int clampi(int v, int lo, int hi) {
    return v < lo ? lo : (v > hi ? hi : v);
}
// read element i of a float tensor whose true dtype is decided at runtime
__device__ __forceinline__ float ld1(const void* p, size_t i, int f32) {
    return f32 ? ((const float*)p)[i] : bf2f(((const u16*)p)[i]);
}

// diagnostic marker: u16 pattern repeated also reads as ~same magnitude if out is fp32
__global__ void marker_kernel(u16* out, u16 code) {
    out[threadIdx.x] = code;   // <<<1,16>>>
}

// dtype sniff + launch sentinel. diag[0]=sentinel, diag[1]=fp32 flag, diag[2]=const 0
__global__ void detect_kernel(const void* feat, int* diag) {
    int lane = threadIdx.x;      // 64 threads
    int weird = 0;
    const u16* p = (const u16*)feat;
    for (int i = lane; i < 512; i += 64) {
        float v = bf2f(p[i]);
        float a = fabsf(v);
        if (!(a <= 1e4f) || (a != 0.f && a < 1e-6f)) weird++;  // catches inf/NaN too
    }
#pragma unroll
    for (int off = 32; off > 0; off >>= 1) weird += __shfl_xor(weird, off, 64);
    if (lane == 0) { diag[0] = 123456; diag[1] = (weird > 51) ? 1 : 0; diag[2] = 0; }
}

// rpe score collapse: out[p*4+h] = sum_d Wrpe[p][h*64+d]; out[12+h] = sum_d brpe[h*64+d]
__global__ void rpe_sums_kernel(const void* __restrict__ Wrpe,
                                const void* __restrict__ brpe,
                                float* __restrict__ out, const int* __restrict__ dflag) {
    int f32 = dflag[0];
    int t = threadIdx.x;
    if (t < 12) {
        int p = t >> 2, h = t & 3;
        float s = 0.f;
        for (int d = 0; d < 64; ++d) s += ld1(Wrpe, p * 256 + h * 64 + d, f32);
        out[t] = s;
    } else if (t < 16) {
        int h = t - 12;
        float s = 0.f;
        for (int d = 0; d < 64; ++d) s += ld1(brpe, h * 64 + d, f32);
        out[12 + h] = s;
    }
}

// ---------------------------------------------------------------- CSR build
__global__ __launch_bounds__(256) void count_kernel(
        const int* __restrict__ g0, const int* __restrict__ g1,
        const int* __restrict__ g2, const int* __restrict__ g3,
        int* __restrict__ deg) {
    int idx = blockIdx.x * blockDim.x + threadIdx.x;
    if (idx >= 4 * N_EDGES) return;
    int gi = idx / N_EDGES, e = idx - gi * N_EDGES;
    const int* g = (gi == 0) ? g0 : (gi == 1) ? g1 : (gi == 2) ? g2 : g3;
    int dst = clampi(g[e], 0, N_NODES - 1);          // g row 0 = dst
    atomicAdd(&deg[gi * N_NODES + dst], 1);
}

__global__ __launch_bounds__(256) void scan_kernel(int* __restrict__ cur,
                                                   int* __restrict__ rowptr) {
    int g = blockIdx.x;
    int tid = threadIdx.x;
    __shared__ int buf[256];
    int* deg = cur + g * N_NODES;
    int* rp  = rowptr + g * (N_NODES + 1);
    const int CH = (N_NODES + 255) / 256;            // 79
    int lo = tid * CH;
    int hi = lo + CH; if (hi > N_NODES) hi = N_NODES;
    int s = 0;
    for (int i = lo; i < hi; ++i) s += deg[i];
    buf[tid] = s;
    __syncthreads();
    for (int off = 1; off < 256; off <<= 1) {
        int x = (tid >= off) ? buf[tid - off] : 0;
        __syncthreads();
        buf[tid] += x;
        __syncthreads();
    }
    int run = (tid == 0) ? 0 : buf[tid - 1];
    for (int i = lo; i < hi; ++i) {
        int v = deg[i];
        rp[i]  = run;
        deg[i] = run;
        run += v;
    }
    if (tid == 255) rp[N_NODES] = buf[255];
}

__global__ __launch_bounds__(256) void fill_kernel(
        const int* __restrict__ g0, const int* __restrict__ g1,
        const int* __restrict__ g2, const int* __restrict__ g3,
        int* __restrict__ cur, int* __restrict__ col) {
    int idx = blockIdx.x * blockDim.x + threadIdx.x;
    if (idx >= 4 * N_EDGES) return;
    int gi = idx / N_EDGES, e = idx - gi * N_EDGES;
    const int* g = (gi == 0) ? g0 : (gi == 1) ? g1 : (gi == 2) ? g2 : g3;
    int dst = clampi(g[e], 0, N_NODES - 1);
    int src = clampi(g[N_EDGES + e], 0, N_NODES - 1);
    int pos = atomicAdd(&cur[gi * N_NODES + dst], 1);
    if (pos >= 0 && pos < N_EDGES)
        col[gi * N_EDGES + pos] = src;
}

// ---------------------------------------------------------------- dual-dtype GEMM
// C[M,N] = A[M,K] @ B[K,N] + bias; A/B/bias/C dtypes chosen by runtime flags.
// All offsets are in ELEMENTS of the respective runtime dtype.
__global__ __launch_bounds__(256) void gemm_dual(
        const void* __restrict__ A, size_t aoff, int lda, const int* __restrict__ aflag,
        const void* __restrict__ B, size_t boff, int ldb,
        const void* __restrict__ bias, size_t biasoff, const int* __restrict__ bflag,
        void* __restrict__ Cmat, size_t coff, int ldc, const int* __restrict__ cflag,
        int M, int N, int K) {
    __shared__ float As[16][68];  // [k][m], padded
    __shared__ float Bs[16][68];  // [k][n], padded
    int f32a = aflag[0], f32b = bflag[0], f32c = cflag[0];
    int t  = threadIdx.x;
    int tx = t & 15, ty = t >> 4;
    int n0 = blockIdx.x * 64, m0 = blockIdx.y * 64;
    float acc[4][4] = {};
    int ar = t >> 2;          // A row within tile (0..63)
    int ac = (t & 3) * 4;     // A k-offset (0,4,8,12)
    int bk = t >> 4;          // B k row (0..15)
    int bn = (t & 15) * 4;    // B n-offset

    for (int k0 = 0; k0 < K; k0 += 16) {
        float a0 = 0.f, a1 = 0.f, a2 = 0.f, a3 = 0.f;
        int row = m0 + ar;
        if (row < M) {
            size_t ia = aoff + (size_t)row * lda + k0 + ac;
            if (f32a) {
                float4 u = *(const float4*)((const float*)A + ia);
                a0 = u.x; a1 = u.y; a2 = u.z; a3 = u.w;
            } else {
                ushort4 u = *(const ushort4*)((const u16*)A + ia);
                a0 = bf2f(u.x); a1 = bf2f(u.y); a2 = bf2f(u.z); a3 = bf2f(u.w);
            }
        }
        float b0, b1, b2, b3;
        {
            size_t ib = boff + (size_t)(k0 + bk) * ldb + n0 + bn;
            if (f32b) {
                float4 u = *(const float4*)((const float*)B + ib);
                b0 = u.x; b1 = u.y; b2 = u.z; b3 = u.w;
            } else {
                ushort4 u = *(const ushort4*)((const u16*)B + ib);
                b0 = bf2f(u.x); b1 = bf2f(u.y); b2 = bf2f(u.z); b3 = bf2f(u.w);
            }
        }
        __syncthreads();
        As[ac + 0][ar] = a0; As[ac + 1][ar] = a1; As[ac + 2][ar] = a2; As[ac + 3][ar] = a3;
        *(float4*)&Bs[bk][bn] = make_float4(b0, b1, b2, b3);
        __syncthreads();
#pragma unroll
        for (int kk = 0; kk < 16; ++kk) {
            float4 av = *(float4*)&As[kk][ty * 4];
            float4 bv = *(float4*)&Bs[kk][tx * 4];
            acc[0][0] += av.x * bv.x; acc[0][1] += av.x * bv.y; acc[0][2] += av.x * bv.z; acc[0][3] += av.x * bv.w;
            acc[1][0] += av.y * bv.x; acc[1][1] += av.y * bv.y; acc[1][2] += av.y * bv.z; acc[1][3] += av.y * bv.w;
            acc[2][0] += av.z * bv.x; acc[2][1] += av.z * bv.y; acc[2][2] += av.z * bv.z; acc[2][3] += av.z * bv.w;
            acc[3][0] += av.w * bv.x; acc[3][1] += av.w * bv.y; acc[3][2] += av.w * bv.z; acc[3][3] += av.w * bv.w;
        }
    }
    float bb0 = ld1(bias, biasoff + n0 + tx * 4 + 0, f32b);
    float bb1 = ld1(bias, biasoff + n0 + tx * 4 + 1, f32b);
    float bb2 = ld1(bias, biasoff + n0 + tx * 4 + 2, f32b);
    float bb3 = ld1(bias, biasoff + n0 + tx * 4 + 3, f32b);
#pragma unroll
    for (int i = 0; i < 4; ++i) {
        int row = m0 + ty * 4 + i;
        if (row < M) {
            size_t ic = coff + (size_t)row * ldc + n0 + tx * 4;
            float o0 = acc[i][0] + bb0, o1 = acc[i][1] + bb1;
            float o2 = acc[i][2] + bb2, o3 = acc[i][3] + bb3;
            if (f32c) {
                *(float4*)((float*)Cmat + ic) = make_float4(o0, o1, o2, o3);
            } else {
                ushort4 o; o.x = f2bf(o0); o.y = f2bf(o1); o.z = f2bf(o2); o.w = f2bf(o3);
                *(ushort4*)((u16*)Cmat + ic) = o;
            }
        }
    }
}

// ---------------------------------------------------------------- edge attention
// one wave per dst node; lane = d (0..63); 4 heads in 4 regs. T/cat always bf16.
__global__ __launch_bounds__(256) void attn_kernel(
    const u16* __restrict__ Q, int qstride,
    const u16* __restrict__ Kk, const u16* __restrict__ V, int kvstride,
    const int* __restrict__ rowptr, const int* __restrict__ col,
    const void* __restrict__ coordD, const void* __restrict__ coordS,
    const int* __restrict__ dflag,
    const float* __restrict__ rpe_sums, int use_rpe,
    u16* __restrict__ out, int ostride) {
    int lane = threadIdx.x & 63;
    int node = blockIdx.x * 4 + (threadIdx.x >> 6);
    if (node >= N_NODES) return;
    int f32 = dflag[0];

    const u16* qr = Q + (size_t)node * qstride;
    float qf0 = bf2f(qr[lane]);
    float qf1 = bf2f(qr[64 + lane]);
    float qf2 = bf2f(qr[128 + lane]);
    float qf3 = bf2f(qr[192 + lane]);

    float cd0 = 0.f, cd1 = 0.f, cd2 = 0.f;
    float w00 = 0, w01 = 0, w02 = 0, w03 = 0;
    float w10 = 0, w11 = 0, w12 = 0, w13 = 0;
    float w20 = 0, w21 = 0, w22 = 0, w23 = 0;
    float rb0 = 0, rb1 = 0, rb2 = 0, rb3 = 0;
    if (use_rpe) {
        cd0 = ld1(coordD, (size_t)node * 3 + 0, f32);
        cd1 = ld1(coordD, (size_t)node * 3 + 1, f32);
        cd2 = ld1(coordD, (size_t)node * 3 + 2, f32);
        w00 = rpe_sums[0];  w01 = rpe_sums[1];  w02 = rpe_sums[2];  w03 = rpe_sums[3];
        w10 = rpe_sums[4];  w11 = rpe_sums[5];  w12 = rpe_sums[6];  w13 = rpe_sums[7];
        w20 = rpe_sums[8];  w21 = rpe_sums[9];  w22 = rpe_sums[10]; w23 = rpe_sums[11];
        rb0 = rpe_sums[12]; rb1 = rpe_sums[13]; rb2 = rpe_sums[14]; rb3 = rpe_sums[15];
    }

    float m0 = -1e30f, m1 = -1e30f, m2 = -1e30f, m3 = -1e30f;
    float l0 = 0.f, l1 = 0.f, l2 = 0.f, l3 = 0.f;
    float a0 = 0.f, a1 = 0.f, a2 = 0.f, a3 = 0.f;

    int e0 = rowptr[node], e1 = rowptr[node + 1];
    e0 = clampi(e0, 0, N_EDGES);
    e1 = clampi(e1, e0, N_EDGES);
    for (int e = e0; e < e1; ++e) {
        int src = clampi(col[e], 0, N_NODES - 1);
        const u16* kr = Kk + (size_t)src * kvstride;
        const u16* vr = V + (size_t)src * kvstride;
        float t0 = qf0 * bf2f(kr[lane]);
        float t1 = qf1 * bf2f(kr[64 + lane]);
        float t2 = qf2 * bf2f(kr[128 + lane]);
        float t3 = qf3 * bf2f(kr[192 + lane]);
        float v0 = bf2f(vr[lane]);
        float v1 = bf2f(vr[64 + lane]);
        float v2 = bf2f(vr[128 + lane]);
        float v3 = bf2f(vr[192 + lane]);
#pragma unroll
        for (int off = 32; off > 0; off >>= 1) {
            t0 += __shfl_xor(t0, off, 64);
            t1 += __shfl_xor(t1, off, 64);
            t2 += __shfl_xor(t2, off, 64);
            t3 += __shfl_xor(t3, off, 64);
        }
        if (use_rpe) {
            float d0 = cd0 - ld1(coordS, (size_t)src * 3 + 0, f32);
            float d1 = cd1 - ld1(coordS, (size_t)src * 3 + 1, f32);
            float d2 = cd2 - ld1(coordS, (size_t)src * 3 + 2, f32);
            t0 += d0 * w00 + d1 * w10 + d2 * w20 + rb0;
            t1 += d0 * w01 + d1 * w11 + d2 * w21 + rb1;
            t2 += d0 * w02 + d1 * w12 + d2 * w22 + rb2;
            t3 += d0 * w03 + d1 * w13 + d2 * w23 + rb3;
        }
        { float mn = fmaxf(m0, t0); float sc = __expf(m0 - mn); float p = __expf(t0 - mn);
          l0 = l0 * sc + p; a0 = a0 * sc + p * v0; m0 = mn; }
        { float mn = fmaxf(m1, t1); float sc = __expf(m1 - mn); float p = __expf(t1 - mn);
          l1 = l1 * sc + p; a1 = a1 * sc + p * v1; m1 = mn; }
        { float mn = fmaxf(m2, t2); float sc = __expf(m2 - mn); float p = __expf(t2 - mn);
          l2 = l2 * sc + p; a2 = a2 * sc + p * v2; m2 = mn; }
        { float mn = fmaxf(m3, t3); float sc = __expf(m3 - mn); float p = __expf(t3 - mn);
          l3 = l3 * sc + p; a3 = a3 * sc + p * v3; m3 = mn; }
    }

    u16* orow = out + (size_t)node * ostride;
    orow[lane]       = f2bf(l0 > 0.f ? a0 / l0 : 0.f);
    orow[64 + lane]  = f2bf(l1 > 0.f ? a1 / l1 : 0.f);
    orow[128 + lane] = f2bf(l2 > 0.f ? a2 / l2 : 0.f);
    orow[192 + lane] = f2bf(l3 > 0.f ? a3 / l3 : 0.f);
}

// finite-masked max over the first n bf16 elements of a ws buffer
__global__ __launch_bounds__(256) void probe_kernel(const u16* __restrict__ buf, int n,
                                                    float* __restrict__ res) {
    __shared__ float red[256];
    int tid = threadIdx.x;
    float mx = 0.f;
    for (int i = tid; i < n; i += 256) {
        float v = bf2f(buf[i]);
        float a = fabsf(v);
        if (a <= 1e30f) mx = fmaxf(mx, a);
    }
    red[tid] = mx;
    __syncthreads();
    for (int off = 128; off > 0; off >>= 1) {
        if (tid < off) red[tid] = fmaxf(red[tid], red[tid + off]);
        __syncthreads();
    }
    if (tid == 0) *res = red[0];
}

// final check (runs LAST); u16 pattern repeated reads ~same magnitude if out is fp32:
//  0x4680 -> ~16384 sentinel missing | 0x4500 -> ~2048 rowptr bad | 0x4580 -> ~4096 col bad
//  0x4600 -> ~8192 T dead (gemm)     | 0x4700 -> ~32768 cat dead (attn)
__global__ __launch_bounds__(256) void final_check_kernel(
        const int* __restrict__ diag, const float* __restrict__ diagf,
        const int* __restrict__ rowptr, const int* __restrict__ col,
        u16* __restrict__ out) {
    __shared__ int redi[256];
    int tid = threadIdx.x;
    int bad = 0;
    for (int i = tid; i < 4096; i += 256) {
        int c = col[(size_t)i * 311];
        if (c < 0 || c >= N_NODES) bad = 1;
    }
    redi[tid] = bad;
    __syncthreads();
    for (int off = 128; off > 0; off >>= 1) {
        if (tid < off) redi[tid] |= redi[tid + off];
        __syncthreads();
    }
    if (tid == 0) {
        u16 code = 0;
        if (diag[0] != 123456) code = 0x4680;
        else {
            bool rp_ok = true;
            for (int g = 0; g < 4; ++g)
                if (rowptr[g * (N_NODES + 1) + N_NODES] != N_EDGES) rp_ok = false;
            if (!rp_ok) code = 0x4500;
            else if (redi[0]) code = 0x4580;
            else if (diagf[0] < 1e-20f) code = 0x4600;
            else if (diagf[1] < 1e-20f) code = 0x4700;
        }
        if (code) for (int i = 0; i < 16; ++i) out[i] = code;
    }
}

// ---------------------------------------------------------------- launch
extern "C" void kernel_launch(void* const* d_in, const int* in_sizes, int n_in,
                              void* d_out, int out_size, void* d_ws, size_t ws_size,
                              hipStream_t stream) {
    const void* feat1  = d_in[0];
    const void* coord1 = d_in[1];
    const void* feat2  = d_in[2];
    const void* coord2 = d_in[3];
    const void* Wqkv1  = d_in[4];
    const void* bqkv1  = d_in[5];
    const void* Wqkv2  = d_in[6];
    const void* bqkv2  = d_in[7];
    const void* Wproj1 = d_in[8];
    const void* bproj1 = d_in[9];
    const void* Wproj2 = d_in[10];
    const void* bproj2 = d_in[11];
    const void* Wrpe   = d_in[12];
    const void* brpe   = d_in[13];
    const int* graph1  = (const int*)d_in[14];
    const int* graph2  = (const int*)d_in[15];
    const int* graph12 = (const int*)d_in[16];
    const int* graph21 = (const int*)d_in[17];
    u16* out = (u16*)d_out;

    {   // layout assertion (element counts are dtype-independent)
        static const int expect[18] = {
            N_NODES * 256, N_NODES * 3, N_NODES * 256, N_NODES * 3,
            256 * 1536, 1536, 256 * 1536, 1536,
            512 * 256, 256, 512 * 256, 256,
            3 * 256, 256,
            2 * N_EDGES, 2 * N_EDGES, 2 * N_EDGES, 2 * N_EDGES };
        bool ok = (n_in == 18) && (out_size == 2 * N_NODES * 256);
        if (ok) for (int i = 0; i < 18; ++i) if (in_sizes[i] != expect[i]) ok = false;
        if (!ok) { marker_kernel<<<1, 16, 0, stream>>>(out, 0x4496 /*~1200*/); return; }
    }

    char* w = (char*)d_ws;
    size_t off = 0;
    auto alloc = [&](size_t bytes) { void* p = w + off; off += (bytes + 255) & ~(size_t)255; return p; };
    u16* T      = (u16*)alloc((size_t)N_NODES * 768 * 2);   // bf16 [q|k|v]
    u16* cat    = (u16*)alloc((size_t)N_NODES * 512 * 2);   // bf16 [self|cross]
    int* rowptr = (int*)alloc(4ull * (N_NODES + 1) * 4);
    int* cur    = (int*)alloc(4ull * N_NODES * 4);
    int* col    = (int*)alloc(4ull * N_EDGES * 4);
    float* rpe_s = (float*)alloc(64);
    int* diag   = (int*)alloc(256);                          // [0] sentinel [1] f32flag [2] zero
    float* diagf = (float*)(diag + 8);                       // [0] maxT [1] maxCat
    if (off > ws_size) {
        marker_kernel<<<1, 16, 0, stream>>>(out, 0x447A /*~1000*/);
        return;
    }
    const int* dF = diag + 1;   // runtime input-dtype flag
    const int* dZ = diag + 2;   // constant 0 = "bf16"

    const int NP1 = N_NODES + 1;
    hipMemsetAsync(cur, 0, 4ull * N_NODES * 4, stream);
    hipMemsetAsync(diag, 0, 256, stream);

    detect_kernel<<<1, 64, 0, stream>>>(feat1, diag);
    rpe_sums_kernel<<<1, 64, 0, stream>>>(Wrpe, brpe, rpe_s, dF);
    count_kernel<<<(4 * N_EDGES + 255) / 256, 256, 0, stream>>>(graph1, graph2, graph12, graph21, cur);
    scan_kernel<<<4, 256, 0, stream>>>(cur, rowptr);
    fill_kernel<<<(4 * N_EDGES + 255) / 256, 256, 0, stream>>>(graph1, graph2, graph12, graph21, cur, col);

    const dim3 blk(256);
    const int MY = (N_NODES + 63) / 64;   // 313
    const int AG = (N_NODES + 3) / 4;     // attention grid

    // ---- set1 self: T = feat1 @ Wqkv1[:,0:768]
    gemm_dual<<<dim3(12, MY), blk, 0, stream>>>(feat1, 0, 256, dF, Wqkv1, 0, 1536,
                                                bqkv1, 0, dF, T, 0, 768, dZ, N_NODES, 768, 256);
    probe_kernel<<<1, 256, 0, stream>>>(T, 16384, diagf + 0);
    attn_kernel<<<AG, blk, 0, stream>>>(T, 768, T + 256, T + 512, 768,
                                        rowptr + 0 * NP1, col + 0 * N_EDGES,
                                        coord1, coord1, dF, rpe_s, 1, cat + 0, 512);
    probe_kernel<<<1, 256, 0, stream>>>(cat, 16384, diagf + 1);
    // ---- cross 1<-2: {q12, k21, v21}
    gemm_dual<<<dim3(4, MY), blk, 0, stream>>>(feat1, 0, 256, dF, Wqkv1, 768, 1536,
                                               bqkv1, 768, dF, T, 0, 768, dZ, N_NODES, 256, 256);
    gemm_dual<<<dim3(8, MY), blk, 0, stream>>>(feat2, 0, 256, dF, Wqkv2, 256, 1536,
                                               bqkv2, 256, dF, T, 256, 768, dZ, N_NODES, 512, 256);
    attn_kernel<<<AG, blk, 0, stream>>>(T, 768, T + 256, T + 512, 768,
                                        rowptr + 3 * NP1, col + 3 * N_EDGES,
                                        nullptr, nullptr, dF, rpe_s, 0, cat + 256, 512);
    // ---- out1
    gemm_dual<<<dim3(4, MY), blk, 0, stream>>>(cat, 0, 512, dZ, Wproj1, 0, 256,
                                               bproj1, 0, dF, out, 0, 256, dF, N_NODES, 256, 512);

    // ---- set2 self: T = feat2 @ Wqkv2[:,768:1536]
    gemm_dual<<<dim3(12, MY), blk, 0, stream>>>(feat2, 0, 256, dF, Wqkv2, 768, 1536,
                                                bqkv2, 768, dF, T, 0, 768, dZ, N_NODES, 768, 256);
    attn_kernel<<<AG, blk, 0, stream>>>(T, 768, T + 256, T + 512, 768,
                                        rowptr + 1 * NP1, col + 1 * N_EDGES,
                                        coord2, coord2, dF, rpe_s, 1, cat + 0, 512);
    // ---- cross 2<-1: {q21, k12, v12}
    gemm_dual<<<dim3(4, MY), blk, 0, stream>>>(feat2, 0, 256, dF, Wqkv2, 0, 1536,
                                               bqkv2, 0, dF, T, 0, 768, dZ, N_NODES, 256, 256);
    gemm_dual<<<dim3(8, MY), blk, 0, stream>>>(feat1, 0, 256, dF, Wqkv1, 1024, 1536,
                                               bqkv1, 1024, dF, T, 256, 768, dZ, N_NODES, 512, 256);
    attn_kernel<<<AG, blk, 0, stream>>>(T, 768, T + 256, T + 512, 768,
                                        rowptr + 2 * NP1, col + 2 * N_EDGES,
                                        nullptr, nullptr, dF, rpe_s, 0, cat + 256, 512);
    // ---- out2 (element offset works for both dtypes)
    gemm_dual<<<dim3(4, MY), blk, 0, stream>>>(cat, 0, 512, dZ, Wproj2, 0, 256,
                                               bproj2, 0, dF, out, (size_t)N_NODES * 256, 256, dF,
                                               N_NODES, 256, 512);

    final_check_kernel<<<1, 256, 0, stream>>>(diag, diagf, rowptr, col, out);
}

// Round 6
// 879.288 us; speedup vs baseline: 1.6797x; 1.6797x over previous
//
#include <hip/hip_runtime.h>
#include <stdint.h>
#include <stddef.h>

#define N_NODES 20000
#define N_EDGES 320000

typedef unsigned short u16;
typedef __attribute__((ext_vector_type(8))) short bf16x8;
typedef __attribute__((ext_vector_type(8))) unsigned short u16x8;
typedef __attribute__((ext_vector_type(4))) float f32x4;

__device__ __forceinline__ float bf2f(u16 u) {
    union { unsigned int i; float f; } v; v.i = ((unsigned int)u) << 16; return v.f;
}
__device__ __forceinline__ u16 f2bf(float f) {
    union { float f; unsigned int i; } v; v.f = f;
    unsigned int x = v.i;
    unsigned int r = x + 0x7fffu + ((x >> 16) & 1u);
    return (u16)(r >> 16);
}
__device__ __forceinline__ int clampi(int v, int lo, int hi) {
    return v < lo ? lo : (v > hi ? hi : v);
}
__device__ __forceinline__ float ld1(const void* p, size_t i, int f32) {
    return f32 ? ((const float*)p)[i] : bf2f(((const u16*)p)[i]);
}

__global__ void marker_kernel(u16* out, u16 code) { out[threadIdx.x] = code; }

// dtype sniff + sentinel. diag[0]=sentinel, diag[1]=fp32 flag, diag[2]=const 0
__global__ void detect_kernel(const void* feat, int* diag) {
    int lane = threadIdx.x;
    int weird = 0;
    const u16* p = (const u16*)feat;
    for (int i = lane; i < 512; i += 64) {
        float v = bf2f(p[i]);
        float a = fabsf(v);
        if (!(a <= 1e4f) || (a != 0.f && a < 1e-6f)) weird++;
    }
#pragma unroll
    for (int off = 32; off > 0; off >>= 1) weird += __shfl_xor(weird, off, 64);
    if (lane == 0) { diag[0] = 123456; diag[1] = (weird > 51) ? 1 : 0; diag[2] = 0; }
}

// rpe collapse: out[p*4+h] = sum_d Wrpe[p][h*64+d]; out[12+h] = sum_d brpe[h*64+d]
__global__ void rpe_sums_kernel(const void* __restrict__ Wrpe, const void* __restrict__ brpe,
                                float* __restrict__ out, const int* __restrict__ dflag) {
    int f32 = dflag[0];
    int t = threadIdx.x;
    if (t < 12) {
        int p = t >> 2, h = t & 3;
        float s = 0.f;
        for (int d = 0; d < 64; ++d) s += ld1(Wrpe, p * 256 + h * 64 + d, f32);
        out[t] = s;
    } else if (t < 16) {
        int h = t - 12;
        float s = 0.f;
        for (int d = 0; d < 64; ++d) s += ld1(brpe, h * 64 + d, f32);
        out[12 + h] = s;
    }
}

// proj[n*4+h] = sum_p coord[n,p] * rpe_sums[p*4+h]
__global__ __launch_bounds__(256) void coordproj_kernel(const void* __restrict__ coord,
                                                        const int* __restrict__ dflag,
                                                        const float* __restrict__ rs,
                                                        float* __restrict__ proj, int n) {
    int i = blockIdx.x * 256 + threadIdx.x;
    if (i >= n * 4) return;
    int f32 = dflag[0];
    int node = i >> 2, h = i & 3;
    float s = ld1(coord, (size_t)node * 3 + 0, f32) * rs[0 * 4 + h]
            + ld1(coord, (size_t)node * 3 + 1, f32) * rs[1 * 4 + h]
            + ld1(coord, (size_t)node * 3 + 2, f32) * rs[2 * 4 + h];
    proj[i] = s;
}

// Wt[n*K + k] = bf16(W[k*N + n])  (weight transpose + convert)
__global__ __launch_bounds__(256) void transpose_w_kernel(const void* __restrict__ W,
                                                          const int* __restrict__ dflag,
                                                          u16* __restrict__ Wt, int K, int N) {
    int f32 = dflag[0];
    int i = blockIdx.x * 256 + threadIdx.x;
    if (i >= K * N) return;
    int n = i / K, k = i - n * K;
    Wt[i] = f2bf(ld1(W, (size_t)k * N + n, f32));
}

// ---------------------------------------------------------------- CSR build
__global__ __launch_bounds__(256) void count_kernel(
        const int* __restrict__ g0, const int* __restrict__ g1,
        const int* __restrict__ g2, const int* __restrict__ g3,
        int* __restrict__ deg) {
    int idx = blockIdx.x * blockDim.x + threadIdx.x;
    if (idx >= 4 * N_EDGES) return;
    int gi = idx / N_EDGES, e = idx - gi * N_EDGES;
    const int* g = (gi == 0) ? g0 : (gi == 1) ? g1 : (gi == 2) ? g2 : g3;
    int dst = clampi(g[e], 0, N_NODES - 1);
    atomicAdd(&deg[gi * N_NODES + dst], 1);
}

__global__ __launch_bounds__(256) void scan_kernel(int* __restrict__ cur,
                                                   int* __restrict__ rowptr) {
    int g = blockIdx.x;
    int tid = threadIdx.x;
    __shared__ int buf[256];
    int* deg = cur + g * N_NODES;
    int* rp  = rowptr + g * (N_NODES + 1);
    const int CH = (N_NODES + 255) / 256;
    int lo = tid * CH;
    int hi = lo + CH; if (hi > N_NODES) hi = N_NODES;
    int s = 0;
    for (int i = lo; i < hi; ++i) s += deg[i];
    buf[tid] = s;
    __syncthreads();
    for (int off = 1; off < 256; off <<= 1) {
        int x = (tid >= off) ? buf[tid - off] : 0;
        __syncthreads();
        buf[tid] += x;
        __syncthreads();
    }
    int run = (tid == 0) ? 0 : buf[tid - 1];
    for (int i = lo; i < hi; ++i) {
        int v = deg[i];
        rp[i]  = run;
        deg[i] = run;
        run += v;
    }
    if (tid == 255) rp[N_NODES] = buf[255];
}

__global__ __launch_bounds__(256) void fill_kernel(
        const int* __restrict__ g0, const int* __restrict__ g1,
        const int* __restrict__ g2, const int* __restrict__ g3,
        int* __restrict__ cur, int* __restrict__ col) {
    int idx = blockIdx.x * blockDim.x + threadIdx.x;
    if (idx >= 4 * N_EDGES) return;
    int gi = idx / N_EDGES, e = idx - gi * N_EDGES;
    const int* g = (gi == 0) ? g0 : (gi == 1) ? g1 : (gi == 2) ? g2 : g3;
    int dst = clampi(g[e], 0, N_NODES - 1);
    int src = clampi(g[N_EDGES + e], 0, N_NODES - 1);
    int pos = atomicAdd(&cur[gi * N_NODES + dst], 1);
    if (pos >= 0 && pos < N_EDGES)
        col[gi * N_EDGES + pos] = src;
}

// ---------------------------------------------------------------- MFMA GEMM
// C[M,N] = A[M,K] @ Bt[N,K]^T + bias.  128x128 tile, BK=32, 4 waves (2x2 of 64x64).
// A: fp32 or bf16 (runtime aflag). Bt: bf16 pre-transposed [N rows][K]. bias: raw (bflag).
// C: fp32 or bf16 (cflag).
__global__ __launch_bounds__(256) void gemm_mfma(
        const void* __restrict__ A, int lda, const int* __restrict__ aflag,
        const u16* __restrict__ Bt,
        const void* __restrict__ bias, size_t biasoff, const int* __restrict__ bflag,
        void* __restrict__ C, size_t coff, int ldc, const int* __restrict__ cflag,
        int M, int N, int K) {
    __shared__ __align__(16) u16 As[128 * 40];
    __shared__ __align__(16) u16 Bs[128 * 40];
    const int f32a = aflag[0], f32b = bflag[0], f32c = cflag[0];
    const int t = threadIdx.x;
    const int lane = t & 63, wv = t >> 6;
    const int wm = (wv >> 1) * 64, wn = (wv & 1) * 64;
    const int m0 = blockIdx.y * 128, n0 = blockIdx.x * 128;
    const int l15 = lane & 15, lq = lane >> 4;

    f32x4 acc[4][4];
#pragma unroll
    for (int i = 0; i < 4; ++i)
#pragma unroll
        for (int j = 0; j < 4; ++j) acc[i][j] = (f32x4){0.f, 0.f, 0.f, 0.f};

    const int sr = t >> 1, skc = (t & 1) * 16;   // staging: row (0..127), k-chunk (0/16)

    for (int k0 = 0; k0 < K; k0 += 32) {
        __syncthreads();
        // ---- stage A rows (m-major, bf16, stride 40)
        {
            __align__(16) u16 tmp[16];
            int gm = m0 + sr;
            if (gm < M) {
                if (f32a) {
                    const float* ap = (const float*)A + (size_t)gm * lda + k0 + skc;
#pragma unroll
                    for (int i = 0; i < 16; i += 4) {
                        float4 u = *(const float4*)(ap + i);
                        tmp[i] = f2bf(u.x); tmp[i + 1] = f2bf(u.y);
                        tmp[i + 2] = f2bf(u.z); tmp[i + 3] = f2bf(u.w);
                    }
                } else {
                    const u16* ap = (const u16*)A + (size_t)gm * lda + k0 + skc;
                    *(u16x8*)&tmp[0] = *(const u16x8*)ap;
                    *(u16x8*)&tmp[8] = *(const u16x8*)(ap + 8);
                }
            } else {
#pragma unroll
                for (int i = 0; i < 16; ++i) tmp[i] = 0;
            }
            *(u16x8*)&As[sr * 40 + skc] = *(u16x8*)&tmp[0];
            *(u16x8*)&As[sr * 40 + skc + 8] = *(u16x8*)&tmp[8];
        }
        // ---- stage B rows (n-major from Wt[N][K], bf16, stride 40)
        {
            const u16* bp = Bt + (size_t)(n0 + sr) * K + k0 + skc;
            u16x8 b0 = *(const u16x8*)bp;
            u16x8 b1 = *(const u16x8*)(bp + 8);
            *(u16x8*)&Bs[sr * 40 + skc] = b0;
            *(u16x8*)&Bs[sr * 40 + skc + 8] = b1;
        }
        __syncthreads();
        // ---- fragments + MFMA
        bf16x8 af[4], bfr[4];
#pragma unroll
        for (int mt = 0; mt < 4; ++mt)
            af[mt] = *(const bf16x8*)&As[(wm + mt * 16 + l15) * 40 + lq * 8];
#pragma unroll
        for (int nt = 0; nt < 4; ++nt)
            bfr[nt] = *(const bf16x8*)&Bs[(wn + nt * 16 + l15) * 40 + lq * 8];
#pragma unroll
        for (int mt = 0; mt < 4; ++mt)
#pragma unroll
            for (int nt = 0; nt < 4; ++nt)
                acc[mt][nt] = __builtin_amdgcn_mfma_f32_16x16x32_bf16(af[mt], bfr[nt], acc[mt][nt], 0, 0, 0);
    }
    // ---- epilogue: C/D layout col=lane&15, row=(lane>>4)*4+reg
#pragma unroll
    for (int mt = 0; mt < 4; ++mt) {
#pragma unroll
        for (int nt = 0; nt < 4; ++nt) {
            int gn = n0 + wn + nt * 16 + l15;
            float bb = ld1(bias, biasoff + gn, f32b);
#pragma unroll
            for (int r = 0; r < 4; ++r) {
                int gm = m0 + wm + mt * 16 + lq * 4 + r;
                if (gm < M) {
                    float v = acc[mt][nt][r] + bb;
                    size_t ic = coff + (size_t)gm * ldc + gn;
                    if (f32c) ((float*)C)[ic] = v;
                    else      ((u16*)C)[ic] = f2bf(v);
                }
            }
        }
    }
}

// ---------------------------------------------------------------- edge attention v2
// wave per dst node; lane = h*16+j; lane owns d = j*4..j*4+3 of head h.
__global__ __launch_bounds__(256) void attn2_kernel(
        const u16* __restrict__ Q, const u16* __restrict__ Kp, const u16* __restrict__ Vp,
        const int* __restrict__ rowptr, const int* __restrict__ col,
        const float* __restrict__ projN, const float* __restrict__ projS,
        const float* __restrict__ rb, int use_rpe,
        u16* __restrict__ outp) {
    int lane = threadIdx.x & 63;
    int node = blockIdx.x * 4 + (threadIdx.x >> 6);
    if (node >= N_NODES) return;
    int h = lane >> 4;
    int off = h * 64 + (lane & 15) * 4;

    ushort4 qu = *(const ushort4*)(Q + (size_t)node * 768 + off);
    float q0 = bf2f(qu.x), q1 = bf2f(qu.y), q2 = bf2f(qu.z), q3 = bf2f(qu.w);
    float base = use_rpe ? (projN[node * 4 + h] + rb[h]) : 0.f;

    float m = -1e30f, l = 0.f, a0 = 0.f, a1 = 0.f, a2 = 0.f, a3 = 0.f;
    int e0 = rowptr[node], e1 = rowptr[node + 1];
    e0 = clampi(e0, 0, N_EDGES);
    e1 = clampi(e1, e0, N_EDGES);
    for (int e = e0; e < e1; ++e) {
        int src = clampi(col[e], 0, N_NODES - 1);
        ushort4 ku = *(const ushort4*)(Kp + (size_t)src * 768 + off);
        float tv = q0 * bf2f(ku.x) + q1 * bf2f(ku.y) + q2 * bf2f(ku.z) + q3 * bf2f(ku.w);
        tv += __shfl_xor(tv, 1, 64);
        tv += __shfl_xor(tv, 2, 64);
        tv += __shfl_xor(tv, 4, 64);
        tv += __shfl_xor(tv, 8, 64);
        if (use_rpe) tv += base - projS[src * 4 + h];
        ushort4 vu = *(const ushort4*)(Vp + (size_t)src * 768 + off);
        float mn = fmaxf(m, tv);
        float sc = __expf(m - mn), p = __expf(tv - mn);
        l = l * sc + p;
        a0 = a0 * sc + p * bf2f(vu.x);
        a1 = a1 * sc + p * bf2f(vu.y);
        a2 = a2 * sc + p * bf2f(vu.z);
        a3 = a3 * sc + p * bf2f(vu.w);
        m = mn;
    }
    float inv = l > 0.f ? 1.f / l : 0.f;
    ushort4 o;
    o.x = f2bf(a0 * inv); o.y = f2bf(a1 * inv); o.z = f2bf(a2 * inv); o.w = f2bf(a3 * inv);
    *(ushort4*)(outp + (size_t)node * 512 + off) = o;
}

// ---------------------------------------------------------------- launch
extern "C" void kernel_launch(void* const* d_in, const int* in_sizes, int n_in,
                              void* d_out, int out_size, void* d_ws, size_t ws_size,
                              hipStream_t stream) {
    const void* feat1  = d_in[0];
    const void* coord1 = d_in[1];
    const void* feat2  = d_in[2];
    const void* coord2 = d_in[3];
    const void* Wqkv1  = d_in[4];
    const void* bqkv1  = d_in[5];
    const void* Wqkv2  = d_in[6];
    const void* bqkv2  = d_in[7];
    const void* Wproj1 = d_in[8];
    const void* bproj1 = d_in[9];
    const void* Wproj2 = d_in[10];
    const void* bproj2 = d_in[11];
    const void* Wrpe   = d_in[12];
    const void* brpe   = d_in[13];
    const int* graph1  = (const int*)d_in[14];
    const int* graph2  = (const int*)d_in[15];
    const int* graph12 = (const int*)d_in[16];
    const int* graph21 = (const int*)d_in[17];
    u16* out = (u16*)d_out;

    {   // layout assertion
        static const int expect[18] = {
            N_NODES * 256, N_NODES * 3, N_NODES * 256, N_NODES * 3,
            256 * 1536, 1536, 256 * 1536, 1536,
            512 * 256, 256, 512 * 256, 256,
            3 * 256, 256,
            2 * N_EDGES, 2 * N_EDGES, 2 * N_EDGES, 2 * N_EDGES };
        bool ok = (n_in == 18) && (out_size == 2 * N_NODES * 256);
        if (ok) for (int i = 0; i < 18; ++i) if (in_sizes[i] != expect[i]) ok = false;
        if (!ok) { marker_kernel<<<1, 16, 0, stream>>>(out, 0x4496 /*~1200*/); return; }
    }

    char* w = (char*)d_ws;
    size_t off = 0;
    auto alloc = [&](size_t bytes) { void* p = w + off; off += (bytes + 255) & ~(size_t)255; return p; };
    u16* T       = (u16*)alloc((size_t)N_NODES * 768 * 2);   // bf16 [q|k|v]
    u16* cat     = (u16*)alloc((size_t)N_NODES * 512 * 2);   // bf16 [self|cross]
    int* rowptr  = (int*)alloc(4ull * (N_NODES + 1) * 4);
    int* cur     = (int*)alloc(4ull * N_NODES * 4);
    int* col     = (int*)alloc(4ull * N_EDGES * 4);
    float* rpe_s = (float*)alloc(64);
    int* diag    = (int*)alloc(256);
    float* proj1 = (float*)alloc((size_t)N_NODES * 4 * 4);
    float* proj2 = (float*)alloc((size_t)N_NODES * 4 * 4);
    u16* Wqkv1t  = (u16*)alloc((size_t)1536 * 256 * 2);
    u16* Wqkv2t  = (u16*)alloc((size_t)1536 * 256 * 2);
    u16* Wproj1t = (u16*)alloc((size_t)256 * 512 * 2);
    u16* Wproj2t = (u16*)alloc((size_t)256 * 512 * 2);
    if (off > ws_size) {   // ~60 MB needed
        marker_kernel<<<1, 16, 0, stream>>>(out, 0x447A /*~1000*/);
        return;
    }
    const int* dF = diag + 1;   // runtime input dtype flag
    const int* dZ = diag + 2;   // constant 0 = bf16

    const int NP1 = N_NODES + 1;
    hipMemsetAsync(cur, 0, 4ull * N_NODES * 4, stream);
    hipMemsetAsync(diag, 0, 256, stream);

    detect_kernel<<<1, 64, 0, stream>>>(feat1, diag);
    rpe_sums_kernel<<<1, 64, 0, stream>>>(Wrpe, brpe, rpe_s, dF);
    coordproj_kernel<<<(N_NODES * 4 + 255) / 256, 256, 0, stream>>>(coord1, dF, rpe_s, proj1, N_NODES);
    coordproj_kernel<<<(N_NODES * 4 + 255) / 256, 256, 0, stream>>>(coord2, dF, rpe_s, proj2, N_NODES);
    transpose_w_kernel<<<(1536 * 256 + 255) / 256, 256, 0, stream>>>(Wqkv1, dF, Wqkv1t, 256, 1536);
    transpose_w_kernel<<<(1536 * 256 + 255) / 256, 256, 0, stream>>>(Wqkv2, dF, Wqkv2t, 256, 1536);
    transpose_w_kernel<<<(256 * 512 + 255) / 256, 256, 0, stream>>>(Wproj1, dF, Wproj1t, 512, 256);
    transpose_w_kernel<<<(256 * 512 + 255) / 256, 256, 0, stream>>>(Wproj2, dF, Wproj2t, 512, 256);

    count_kernel<<<(4 * N_EDGES + 255) / 256, 256, 0, stream>>>(graph1, graph2, graph12, graph21, cur);
    scan_kernel<<<4, 256, 0, stream>>>(cur, rowptr);
    fill_kernel<<<(4 * N_EDGES + 255) / 256, 256, 0, stream>>>(graph1, graph2, graph12, graph21, cur, col);

    const dim3 blk(256);
    const int GY = (N_NODES + 127) / 128;   // 157
    const int AG = (N_NODES + 3) / 4;       // 5000

    // ---- set1 self: T = feat1 @ Wqkv1[:,0:768]
    gemm_mfma<<<dim3(6, GY), blk, 0, stream>>>(feat1, 256, dF, Wqkv1t + 0 * 256,
                                               bqkv1, 0, dF, T, 0, 768, dZ, N_NODES, 768, 256);
    attn2_kernel<<<AG, blk, 0, stream>>>(T, T + 256, T + 512, rowptr + 0 * NP1, col + 0 * N_EDGES,
                                         proj1, proj1, rpe_s + 12, 1, cat + 0);
    // ---- cross 1<-2: {q12, k21, v21}
    gemm_mfma<<<dim3(2, GY), blk, 0, stream>>>(feat1, 256, dF, Wqkv1t + (size_t)768 * 256,
                                               bqkv1, 768, dF, T, 0, 768, dZ, N_NODES, 256, 256);
    gemm_mfma<<<dim3(4, GY), blk, 0, stream>>>(feat2, 256, dF, Wqkv2t + (size_t)256 * 256,
                                               bqkv2, 256, dF, T, 256, 768, dZ, N_NODES, 512, 256);
    attn2_kernel<<<AG, blk, 0, stream>>>(T, T + 256, T + 512, rowptr + 3 * NP1, col + 3 * N_EDGES,
                                         nullptr, nullptr, rpe_s + 12, 0, cat + 256);
    // ---- out1 = cat @ Wproj1 + bproj1
    gemm_mfma<<<dim3(2, GY), blk, 0, stream>>>(cat, 512, dZ, Wproj1t,
                                               bproj1, 0, dF, out, 0, 256, dF, N_NODES, 256, 512);

    // ---- set2 self: T = feat2 @ Wqkv2[:,768:1536]
    gemm_mfma<<<dim3(6, GY), blk, 0, stream>>>(feat2, 256, dF, Wqkv2t + (size_t)768 * 256,
                                               bqkv2, 768, dF, T, 0, 768, dZ, N_NODES, 768, 256);
    attn2_kernel<<<AG, blk, 0, stream>>>(T, T + 256, T + 512, rowptr + 1 * NP1, col + 1 * N_EDGES,
                                         proj2, proj2, rpe_s + 12, 1, cat + 0);
    // ---- cross 2<-1: {q21, k12, v12}
    gemm_mfma<<<dim3(2, GY), blk, 0, stream>>>(feat2, 256, dF, Wqkv2t + 0,
                                               bqkv2, 0, dF, T, 0, 768, dZ, N_NODES, 256, 256);
    gemm_mfma<<<dim3(4, GY), blk, 0, stream>>>(feat1, 256, dF, Wqkv1t + (size_t)1024 * 256,
                                               bqkv1, 1024, dF, T, 256, 768, dZ, N_NODES, 512, 256);
    attn2_kernel<<<AG, blk, 0, stream>>>(T, T + 256, T + 512, rowptr + 2 * NP1, col + 2 * N_EDGES,
                                         nullptr, nullptr, rpe_s + 12, 0, cat + 256);
    // ---- out2 = cat @ Wproj2 + bproj2
    gemm_mfma<<<dim3(2, GY), blk, 0, stream>>>(cat, 512, dZ, Wproj2t,
                                               bproj2, 0, dF, out, (size_t)N_NODES * 256, 256, dF,
                                               N_NODES, 256, 512);
}

// Round 7
// 757.804 us; speedup vs baseline: 1.9490x; 1.1603x over previous
//
#include <hip/hip_runtime.h>
#include <stdint.h>
#include <stddef.h>

#define N_NODES 20000
#define N_EDGES 320000

typedef unsigned short u16;
typedef __attribute__((ext_vector_type(8))) short bf16x8;
typedef __attribute__((ext_vector_type(8))) unsigned short u16x8;
typedef __attribute__((ext_vector_type(4))) float f32x4;

__device__ __forceinline__ float bf2f(u16 u) {
    union { unsigned int i; float f; } v; v.i = ((unsigned int)u) << 16; return v.f;
}
__device__ __forceinline__ u16 f2bf(float f) {
    union { float f; unsigned int i; } v; v.f = f;
    unsigned int x = v.i;
    unsigned int r = x + 0x7fffu + ((x >> 16) & 1u);
    return (u16)(r >> 16);
}
__device__ __forceinline__ int clampi(int v, int lo, int hi) {
    return v < lo ? lo : (v > hi ? hi : v);
}
__device__ __forceinline__ float ld1(const void* p, size_t i, int f32) {
    return f32 ? ((const float*)p)[i] : bf2f(((const u16*)p)[i]);
}

__global__ void marker_kernel(u16* out, u16 code) { out[threadIdx.x] = code; }

// dtype sniff + sentinel. diag[0]=sentinel, diag[1]=fp32 flag, diag[2]=const 0
__global__ void detect_kernel(const void* feat, int* diag) {
    int lane = threadIdx.x;
    int weird = 0;
    const u16* p = (const u16*)feat;
    for (int i = lane; i < 512; i += 64) {
        float v = bf2f(p[i]);
        float a = fabsf(v);
        if (!(a <= 1e4f) || (a != 0.f && a < 1e-6f)) weird++;
    }
#pragma unroll
    for (int off = 32; off > 0; off >>= 1) weird += __shfl_xor(weird, off, 64);
    if (lane == 0) { diag[0] = 123456; diag[1] = (weird > 51) ? 1 : 0; diag[2] = 0; }
}

// rpe collapse: out[p*4+h] = sum_d Wrpe[p][h*64+d]; out[12+h] = sum_d brpe[h*64+d]
__global__ void rpe_sums_kernel(const void* __restrict__ Wrpe, const void* __restrict__ brpe,
                                float* __restrict__ out, const int* __restrict__ dflag) {
    int f32 = dflag[0];
    int t = threadIdx.x;
    if (t < 12) {
        int p = t >> 2, h = t & 3;
        float s = 0.f;
        for (int d = 0; d < 64; ++d) s += ld1(Wrpe, p * 256 + h * 64 + d, f32);
        out[t] = s;
    } else if (t < 16) {
        int h = t - 12;
        float s = 0.f;
        for (int d = 0; d < 64; ++d) s += ld1(brpe, h * 64 + d, f32);
        out[12 + h] = s;
    }
}

// proj[n*4+h] = sum_p coord[n,p] * rpe_sums[p*4+h]
__global__ __launch_bounds__(256) void coordproj_kernel(const void* __restrict__ coord,
                                                        const int* __restrict__ dflag,
                                                        const float* __restrict__ rs,
                                                        float* __restrict__ proj, int n) {
    int i = blockIdx.x * 256 + threadIdx.x;
    if (i >= n * 4) return;
    int f32 = dflag[0];
    int node = i >> 2, h = i & 3;
    float s = ld1(coord, (size_t)node * 3 + 0, f32) * rs[0 * 4 + h]
            + ld1(coord, (size_t)node * 3 + 1, f32) * rs[1 * 4 + h]
            + ld1(coord, (size_t)node * 3 + 2, f32) * rs[2 * 4 + h];
    proj[i] = s;
}

// Wt[n*K + k] = bf16(W[k*N + n])  (weight transpose + convert)
__global__ __launch_bounds__(256) void transpose_w_kernel(const void* __restrict__ W,
                                                          const int* __restrict__ dflag,
                                                          u16* __restrict__ Wt, int K, int N) {
    int f32 = dflag[0];
    int i = blockIdx.x * 256 + threadIdx.x;
    if (i >= K * N) return;
    int n = i / K, k = i - n * K;
    Wt[i] = f2bf(ld1(W, (size_t)k * N + n, f32));
}

// ---------------------------------------------------------------- CSR build
__global__ __launch_bounds__(256) void count_kernel(
        const int* __restrict__ g0, const int* __restrict__ g1,
        const int* __restrict__ g2, const int* __restrict__ g3,
        int* __restrict__ deg) {
    int idx = blockIdx.x * blockDim.x + threadIdx.x;
    if (idx >= 4 * N_EDGES) return;
    int gi = idx / N_EDGES, e = idx - gi * N_EDGES;
    const int* g = (gi == 0) ? g0 : (gi == 1) ? g1 : (gi == 2) ? g2 : g3;
    int dst = clampi(g[e], 0, N_NODES - 1);
    atomicAdd(&deg[gi * N_NODES + dst], 1);
}

__global__ __launch_bounds__(256) void scan_kernel(int* __restrict__ cur,
                                                   int* __restrict__ rowptr) {
    int g = blockIdx.x;
    int tid = threadIdx.x;
    __shared__ int buf[256];
    int* deg = cur + g * N_NODES;
    int* rp  = rowptr + g * (N_NODES + 1);
    const int CH = (N_NODES + 255) / 256;
    int lo = tid * CH;
    int hi = lo + CH; if (hi > N_NODES) hi = N_NODES;
    int s = 0;
    for (int i = lo; i < hi; ++i) s += deg[i];
    buf[tid] = s;
    __syncthreads();
    for (int off = 1; off < 256; off <<= 1) {
        int x = (tid >= off) ? buf[tid - off] : 0;
        __syncthreads();
        buf[tid] += x;
        __syncthreads();
    }
    int run = (tid == 0) ? 0 : buf[tid - 1];
    for (int i = lo; i < hi; ++i) {
        int v = deg[i];
        rp[i]  = run;
        deg[i] = run;
        run += v;
    }
    if (tid == 255) rp[N_NODES] = buf[255];
}

__global__ __launch_bounds__(256) void fill_kernel(
        const int* __restrict__ g0, const int* __restrict__ g1,
        const int* __restrict__ g2, const int* __restrict__ g3,
        int* __restrict__ cur, int* __restrict__ col) {
    int idx = blockIdx.x * blockDim.x + threadIdx.x;
    if (idx >= 4 * N_EDGES) return;
    int gi = idx / N_EDGES, e = idx - gi * N_EDGES;
    const int* g = (gi == 0) ? g0 : (gi == 1) ? g1 : (gi == 2) ? g2 : g3;
    int dst = clampi(g[e], 0, N_NODES - 1);
    int src = clampi(g[N_EDGES + e], 0, N_NODES - 1);
    int pos = atomicAdd(&cur[gi * N_NODES + dst], 1);
    if (pos >= 0 && pos < N_EDGES)
        col[gi * N_EDGES + pos] = src;
}

// ---------------------------------------------------------------- MFMA GEMM
// C[M,N] = A[M,K] @ Bt[N,K]^T + bias.  128x128 tile, BK=32, 4 waves (2x2 of 64x64).
__global__ __launch_bounds__(256) void gemm_mfma(
        const void* __restrict__ A, int lda, const int* __restrict__ aflag,
        const u16* __restrict__ Bt,
        const void* __restrict__ bias, size_t biasoff, const int* __restrict__ bflag,
        void* __restrict__ C, size_t coff, int ldc, const int* __restrict__ cflag,
        int M, int N, int K) {
    __shared__ __align__(16) u16 As[128 * 40];
    __shared__ __align__(16) u16 Bs[128 * 40];
    const int f32a = aflag[0], f32b = bflag[0], f32c = cflag[0];
    const int t = threadIdx.x;
    const int lane = t & 63, wv = t >> 6;
    const int wm = (wv >> 1) * 64, wn = (wv & 1) * 64;
    const int m0 = blockIdx.y * 128, n0 = blockIdx.x * 128;
    const int l15 = lane & 15, lq = lane >> 4;

    f32x4 acc[4][4];
#pragma unroll
    for (int i = 0; i < 4; ++i)
#pragma unroll
        for (int j = 0; j < 4; ++j) acc[i][j] = (f32x4){0.f, 0.f, 0.f, 0.f};

    const int sr = t >> 1, skc = (t & 1) * 16;

    for (int k0 = 0; k0 < K; k0 += 32) {
        __syncthreads();
        {
            __align__(16) u16 tmp[16];
            int gm = m0 + sr;
            if (gm < M) {
                if (f32a) {
                    const float* ap = (const float*)A + (size_t)gm * lda + k0 + skc;
#pragma unroll
                    for (int i = 0; i < 16; i += 4) {
                        float4 u = *(const float4*)(ap + i);
                        tmp[i] = f2bf(u.x); tmp[i + 1] = f2bf(u.y);
                        tmp[i + 2] = f2bf(u.z); tmp[i + 3] = f2bf(u.w);
                    }
                } else {
                    const u16* ap = (const u16*)A + (size_t)gm * lda + k0 + skc;
                    *(u16x8*)&tmp[0] = *(const u16x8*)ap;
                    *(u16x8*)&tmp[8] = *(const u16x8*)(ap + 8);
                }
            } else {
#pragma unroll
                for (int i = 0; i < 16; ++i) tmp[i] = 0;
            }
            *(u16x8*)&As[sr * 40 + skc] = *(u16x8*)&tmp[0];
            *(u16x8*)&As[sr * 40 + skc + 8] = *(u16x8*)&tmp[8];
        }
        {
            const u16* bp = Bt + (size_t)(n0 + sr) * K + k0 + skc;
            u16x8 b0 = *(const u16x8*)bp;
            u16x8 b1 = *(const u16x8*)(bp + 8);
            *(u16x8*)&Bs[sr * 40 + skc] = b0;
            *(u16x8*)&Bs[sr * 40 + skc + 8] = b1;
        }
        __syncthreads();
        bf16x8 af[4], bfr[4];
#pragma unroll
        for (int mt = 0; mt < 4; ++mt)
            af[mt] = *(const bf16x8*)&As[(wm + mt * 16 + l15) * 40 + lq * 8];
#pragma unroll
        for (int nt = 0; nt < 4; ++nt)
            bfr[nt] = *(const bf16x8*)&Bs[(wn + nt * 16 + l15) * 40 + lq * 8];
#pragma unroll
        for (int mt = 0; mt < 4; ++mt)
#pragma unroll
            for (int nt = 0; nt < 4; ++nt)
                acc[mt][nt] = __builtin_amdgcn_mfma_f32_16x16x32_bf16(af[mt], bfr[nt], acc[mt][nt], 0, 0, 0);
    }
#pragma unroll
    for (int mt = 0; mt < 4; ++mt) {
#pragma unroll
        for (int nt = 0; nt < 4; ++nt) {
            int gn = n0 + wn + nt * 16 + l15;
            float bb = ld1(bias, biasoff + gn, f32b);
#pragma unroll
            for (int r = 0; r < 4; ++r) {
                int gm = m0 + wm + mt * 16 + lq * 4 + r;
                if (gm < M) {
                    float v = acc[mt][nt][r] + bb;
                    size_t ic = coff + (size_t)gm * ldc + gn;
                    if (f32c) ((float*)C)[ic] = v;
                    else      ((u16*)C)[ic] = f2bf(v);
                }
            }
        }
    }
}

// ---------------------------------------------------------------- edge attention v3
// wave per dst node; lane = h*16+j; lane owns d = j*4..j*4+3 of head h.
// 4x edge unroll: 8 independent gathers in flight, one softmax rescale per chunk.
__global__ __launch_bounds__(256) void attn3_kernel(
        const u16* __restrict__ Q, const u16* __restrict__ Kp, const u16* __restrict__ Vp,
        const int* __restrict__ rowptr, const int* __restrict__ col,
        const float* __restrict__ projN, const float* __restrict__ projS,
        const float* __restrict__ rb, int use_rpe,
        u16* __restrict__ outp) {
    int lane = threadIdx.x & 63;
    int node = blockIdx.x * 4 + (threadIdx.x >> 6);
    if (node >= N_NODES) return;
    int h = lane >> 4;
    int off = h * 64 + (lane & 15) * 4;

    ushort4 qu = *(const ushort4*)(Q + (size_t)node * 768 + off);
    float q0 = bf2f(qu.x), q1 = bf2f(qu.y), q2 = bf2f(qu.z), q3 = bf2f(qu.w);
    float base = use_rpe ? (projN[node * 4 + h] + rb[h]) : 0.f;

    float m = -1e30f, l = 0.f, a0 = 0.f, a1 = 0.f, a2 = 0.f, a3 = 0.f;
    int e0 = rowptr[node], e1 = rowptr[node + 1];
    e0 = clampi(e0, 0, N_EDGES);
    e1 = clampi(e1, e0, N_EDGES);
    int e = e0;
    for (; e + 4 <= e1; e += 4) {
        // ---- issue all index loads, then all gathers (8 outstanding)
        int s0 = clampi(col[e + 0], 0, N_NODES - 1);
        int s1 = clampi(col[e + 1], 0, N_NODES - 1);
        int s2 = clampi(col[e + 2], 0, N_NODES - 1);
        int s3 = clampi(col[e + 3], 0, N_NODES - 1);
        ushort4 k0 = *(const ushort4*)(Kp + (size_t)s0 * 768 + off);
        ushort4 k1 = *(const ushort4*)(Kp + (size_t)s1 * 768 + off);
        ushort4 k2 = *(const ushort4*)(Kp + (size_t)s2 * 768 + off);
        ushort4 k3 = *(const ushort4*)(Kp + (size_t)s3 * 768 + off);
        ushort4 v0 = *(const ushort4*)(Vp + (size_t)s0 * 768 + off);
        ushort4 v1 = *(const ushort4*)(Vp + (size_t)s1 * 768 + off);
        ushort4 v2 = *(const ushort4*)(Vp + (size_t)s2 * 768 + off);
        ushort4 v3 = *(const ushort4*)(Vp + (size_t)s3 * 768 + off);
        float t0 = q0 * bf2f(k0.x) + q1 * bf2f(k0.y) + q2 * bf2f(k0.z) + q3 * bf2f(k0.w);
        float t1 = q0 * bf2f(k1.x) + q1 * bf2f(k1.y) + q2 * bf2f(k1.z) + q3 * bf2f(k1.w);
        float t2 = q0 * bf2f(k2.x) + q1 * bf2f(k2.y) + q2 * bf2f(k2.z) + q3 * bf2f(k2.w);
        float t3 = q0 * bf2f(k3.x) + q1 * bf2f(k3.y) + q2 * bf2f(k3.z) + q3 * bf2f(k3.w);
#pragma unroll
        for (int sh = 1; sh <= 8; sh <<= 1) {
            t0 += __shfl_xor(t0, sh, 64);
            t1 += __shfl_xor(t1, sh, 64);
            t2 += __shfl_xor(t2, sh, 64);
            t3 += __shfl_xor(t3, sh, 64);
        }
        if (use_rpe) {
            t0 += base - projS[s0 * 4 + h];
            t1 += base - projS[s1 * 4 + h];
            t2 += base - projS[s2 * 4 + h];
            t3 += base - projS[s3 * 4 + h];
        }
        float mx = fmaxf(fmaxf(fmaxf(t0, t1), fmaxf(t2, t3)), m);
        float sc = __expf(m - mx);
        float p0 = __expf(t0 - mx), p1 = __expf(t1 - mx);
        float p2 = __expf(t2 - mx), p3 = __expf(t3 - mx);
        l = l * sc + (p0 + p1 + p2 + p3);
        a0 = a0 * sc + p0 * bf2f(v0.x) + p1 * bf2f(v1.x) + p2 * bf2f(v2.x) + p3 * bf2f(v3.x);
        a1 = a1 * sc + p0 * bf2f(v0.y) + p1 * bf2f(v1.y) + p2 * bf2f(v2.y) + p3 * bf2f(v3.y);
        a2 = a2 * sc + p0 * bf2f(v0.z) + p1 * bf2f(v1.z) + p2 * bf2f(v2.z) + p3 * bf2f(v3.z);
        a3 = a3 * sc + p0 * bf2f(v0.w) + p1 * bf2f(v1.w) + p2 * bf2f(v2.w) + p3 * bf2f(v3.w);
        m = mx;
    }
    for (; e < e1; ++e) {
        int src = clampi(col[e], 0, N_NODES - 1);
        ushort4 ku = *(const ushort4*)(Kp + (size_t)src * 768 + off);
        ushort4 vu = *(const ushort4*)(Vp + (size_t)src * 768 + off);
        float tv = q0 * bf2f(ku.x) + q1 * bf2f(ku.y) + q2 * bf2f(ku.z) + q3 * bf2f(ku.w);
        tv += __shfl_xor(tv, 1, 64);
        tv += __shfl_xor(tv, 2, 64);
        tv += __shfl_xor(tv, 4, 64);
        tv += __shfl_xor(tv, 8, 64);
        if (use_rpe) tv += base - projS[src * 4 + h];
        float mn = fmaxf(m, tv);
        float sc = __expf(m - mn), p = __expf(tv - mn);
        l = l * sc + p;
        a0 = a0 * sc + p * bf2f(vu.x);
        a1 = a1 * sc + p * bf2f(vu.y);
        a2 = a2 * sc + p * bf2f(vu.z);
        a3 = a3 * sc + p * bf2f(vu.w);
        m = mn;
    }
    float inv = l > 0.f ? 1.f / l : 0.f;
    ushort4 o;
    o.x = f2bf(a0 * inv); o.y = f2bf(a1 * inv); o.z = f2bf(a2 * inv); o.w = f2bf(a3 * inv);
    *(ushort4*)(outp + (size_t)node * 512 + off) = o;
}

// ---------------------------------------------------------------- launch
extern "C" void kernel_launch(void* const* d_in, const int* in_sizes, int n_in,
                              void* d_out, int out_size, void* d_ws, size_t ws_size,
                              hipStream_t stream) {
    const void* feat1  = d_in[0];
    const void* coord1 = d_in[1];
    const void* feat2  = d_in[2];
    const void* coord2 = d_in[3];
    const void* Wqkv1  = d_in[4];
    const void* bqkv1  = d_in[5];
    const void* Wqkv2  = d_in[6];
    const void* bqkv2  = d_in[7];
    const void* Wproj1 = d_in[8];
    const void* bproj1 = d_in[9];
    const void* Wproj2 = d_in[10];
    const void* bproj2 = d_in[11];
    const void* Wrpe   = d_in[12];
    const void* brpe   = d_in[13];
    const int* graph1  = (const int*)d_in[14];
    const int* graph2  = (const int*)d_in[15];
    const int* graph12 = (const int*)d_in[16];
    const int* graph21 = (const int*)d_in[17];
    u16* out = (u16*)d_out;

    {   // layout assertion
        static const int expect[18] = {
            N_NODES * 256, N_NODES * 3, N_NODES * 256, N_NODES * 3,
            256 * 1536, 1536, 256 * 1536, 1536,
            512 * 256, 256, 512 * 256, 256,
            3 * 256, 256,
            2 * N_EDGES, 2 * N_EDGES, 2 * N_EDGES, 2 * N_EDGES };
        bool ok = (n_in == 18) && (out_size == 2 * N_NODES * 256);
        if (ok) for (int i = 0; i < 18; ++i) if (in_sizes[i] != expect[i]) ok = false;
        if (!ok) { marker_kernel<<<1, 16, 0, stream>>>(out, 0x4496 /*~1200*/); return; }
    }

    char* w = (char*)d_ws;
    size_t off = 0;
    auto alloc = [&](size_t bytes) { void* p = w + off; off += (bytes + 255) & ~(size_t)255; return p; };
    u16* T       = (u16*)alloc((size_t)N_NODES * 768 * 2);
    u16* cat     = (u16*)alloc((size_t)N_NODES * 512 * 2);
    int* rowptr  = (int*)alloc(4ull * (N_NODES + 1) * 4);
    int* cur     = (int*)alloc(4ull * N_NODES * 4);
    int* col     = (int*)alloc(4ull * N_EDGES * 4);
    float* rpe_s = (float*)alloc(64);
    int* diag    = (int*)alloc(256);
    float* proj1 = (float*)alloc((size_t)N_NODES * 4 * 4);
    float* proj2 = (float*)alloc((size_t)N_NODES * 4 * 4);
    u16* Wqkv1t  = (u16*)alloc((size_t)1536 * 256 * 2);
    u16* Wqkv2t  = (u16*)alloc((size_t)1536 * 256 * 2);
    u16* Wproj1t = (u16*)alloc((size_t)256 * 512 * 2);
    u16* Wproj2t = (u16*)alloc((size_t)256 * 512 * 2);
    if (off > ws_size) {
        marker_kernel<<<1, 16, 0, stream>>>(out, 0x447A /*~1000*/);
        return;
    }
    const int* dF = diag + 1;
    const int* dZ = diag + 2;

    const int NP1 = N_NODES + 1;
    hipMemsetAsync(cur, 0, 4ull * N_NODES * 4, stream);
    hipMemsetAsync(diag, 0, 256, stream);

    detect_kernel<<<1, 64, 0, stream>>>(feat1, diag);
    rpe_sums_kernel<<<1, 64, 0, stream>>>(Wrpe, brpe, rpe_s, dF);
    coordproj_kernel<<<(N_NODES * 4 + 255) / 256, 256, 0, stream>>>(coord1, dF, rpe_s, proj1, N_NODES);
    coordproj_kernel<<<(N_NODES * 4 + 255) / 256, 256, 0, stream>>>(coord2, dF, rpe_s, proj2, N_NODES);
    transpose_w_kernel<<<(1536 * 256 + 255) / 256, 256, 0, stream>>>(Wqkv1, dF, Wqkv1t, 256, 1536);
    transpose_w_kernel<<<(1536 * 256 + 255) / 256, 256, 0, stream>>>(Wqkv2, dF, Wqkv2t, 256, 1536);
    transpose_w_kernel<<<(256 * 512 + 255) / 256, 256, 0, stream>>>(Wproj1, dF, Wproj1t, 512, 256);
    transpose_w_kernel<<<(256 * 512 + 255) / 256, 256, 0, stream>>>(Wproj2, dF, Wproj2t, 512, 256);

    count_kernel<<<(4 * N_EDGES + 255) / 256, 256, 0, stream>>>(graph1, graph2, graph12, graph21, cur);
    scan_kernel<<<4, 256, 0, stream>>>(cur, rowptr);
    fill_kernel<<<(4 * N_EDGES + 255) / 256, 256, 0, stream>>>(graph1, graph2, graph12, graph21, cur, col);

    const dim3 blk(256);
    const int GY = (N_NODES + 127) / 128;
    const int AG = (N_NODES + 3) / 4;

    // ---- set1 self: T = feat1 @ Wqkv1[:,0:768]
    gemm_mfma<<<dim3(6, GY), blk, 0, stream>>>(feat1, 256, dF, Wqkv1t + 0 * 256,
                                               bqkv1, 0, dF, T, 0, 768, dZ, N_NODES, 768, 256);
    attn3_kernel<<<AG, blk, 0, stream>>>(T, T + 256, T + 512, rowptr + 0 * NP1, col + 0 * N_EDGES,
                                         proj1, proj1, rpe_s + 12, 1, cat + 0);
    // ---- cross 1<-2: {q12, k21, v21}
    gemm_mfma<<<dim3(2, GY), blk, 0, stream>>>(feat1, 256, dF, Wqkv1t + (size_t)768 * 256,
                                               bqkv1, 768, dF, T, 0, 768, dZ, N_NODES, 256, 256);
    gemm_mfma<<<dim3(4, GY), blk, 0, stream>>>(feat2, 256, dF, Wqkv2t + (size_t)256 * 256,
                                               bqkv2, 256, dF, T, 256, 768, dZ, N_NODES, 512, 256);
    attn3_kernel<<<AG, blk, 0, stream>>>(T, T + 256, T + 512, rowptr + 3 * NP1, col + 3 * N_EDGES,
                                         nullptr, nullptr, rpe_s + 12, 0, cat + 256);
    // ---- out1 = cat @ Wproj1 + bproj1
    gemm_mfma<<<dim3(2, GY), blk, 0, stream>>>(cat, 512, dZ, Wproj1t,
                                               bproj1, 0, dF, out, 0, 256, dF, N_NODES, 256, 512);

    // ---- set2 self: T = feat2 @ Wqkv2[:,768:1536]
    gemm_mfma<<<dim3(6, GY), blk, 0, stream>>>(feat2, 256, dF, Wqkv2t + (size_t)768 * 256,
                                               bqkv2, 768, dF, T, 0, 768, dZ, N_NODES, 768, 256);
    attn3_kernel<<<AG, blk, 0, stream>>>(T, T + 256, T + 512, rowptr + 1 * NP1, col + 1 * N_EDGES,
                                         proj2, proj2, rpe_s + 12, 1, cat + 0);
    // ---- cross 2<-1: {q21, k12, v12}
    gemm_mfma<<<dim3(2, GY), blk, 0, stream>>>(feat2, 256, dF, Wqkv2t + 0,
                                               bqkv2, 0, dF, T, 0, 768, dZ, N_NODES, 256, 256);
    gemm_mfma<<<dim3(4, GY), blk, 0, stream>>>(feat1, 256, dF, Wqkv1t + (size_t)1024 * 256,
                                               bqkv1, 1024, dF, T, 256, 768, dZ, N_NODES, 512, 256);
    attn3_kernel<<<AG, blk, 0, stream>>>(T, T + 256, T + 512, rowptr + 2 * NP1, col + 2 * N_EDGES,
                                         nullptr, nullptr, rpe_s + 12, 0, cat + 256);
    // ---- out2 = cat @ Wproj2 + bproj2
    gemm_mfma<<<dim3(2, GY), blk, 0, stream>>>(cat, 512, dZ, Wproj2t,
                                               bproj2, 0, dF, out, (size_t)N_NODES * 256, 256, dF,
                                               N_NODES, 256, 512);
}